// Round 1
// baseline (173.574 us; speedup 1.0000x reference)
//
#include <hip/hip_runtime.h>
#include <hip/hip_bf16.h>

typedef __bf16 bf16_t;
typedef bf16_t bf16x8 __attribute__((ext_vector_type(8)));
typedef bf16_t bf16x4 __attribute__((ext_vector_type(4)));
typedef float f32x4 __attribute__((ext_vector_type(4)));

#define BB 2
#define SQ 2048
#define SK 2048
#define NH 16
#define HKV 4
#define DD 64
#define GQ (NH / HKV)       // 4
#define MTILE 64            // q rows per block
#define NTILE 64            // kv cols per tile
#define LDK 72              // padded LDS row length (bf16 elems)

__global__ __launch_bounds__(256, 2)
void fattn_kernel(const float* __restrict__ q,
                  const float* __restrict__ kv,
                  const int* __restrict__ mask,
                  float* __restrict__ out)
{
    __shared__ __align__(16) bf16_t Ks[NTILE][LDK];
    __shared__ __align__(16) bf16_t Vt[DD][LDK];
    __shared__ __align__(16) bf16_t Ps[4][16][LDK];
    __shared__ float padv[NTILE];

    const int tid  = threadIdx.x;
    const int wid  = tid >> 6;
    const int lane = tid & 63;
    const int l16  = lane & 15;
    const int lg   = lane >> 4;       // 0..3

    const int bid = blockIdx.x;
    const int qt  = bid % (SQ / MTILE);
    const int bh  = bid / (SQ / MTILE);
    const int h   = bh % NH;
    const int b   = bh / NH;
    const int hk  = h / GQ;

    const int qrow0 = qt * MTILE + wid * 16;
    const float scale = 0.125f;       // 1/sqrt(64)

    // ---- load Q fragments (held in registers for whole kernel) ----
    bf16x8 qf[2];
    {
        const int qrow = qrow0 + l16;
        const float* qp = q + ((size_t)(b * SQ + qrow) * NH + h) * DD;
        #pragma unroll
        for (int kk = 0; kk < 2; ++kk) {
            const int d0 = kk * 32 + lg * 8;
            f32x4 v0 = *(const f32x4*)(qp + d0);
            f32x4 v1 = *(const f32x4*)(qp + d0 + 4);
            #pragma unroll
            for (int j = 0; j < 4; ++j) {
                qf[kk][j]     = (bf16_t)(v0[j] * scale);
                qf[kk][4 + j] = (bf16_t)(v1[j] * scale);
            }
        }
    }

    f32x4 o_acc[4];
    #pragma unroll
    for (int i = 0; i < 4; ++i) o_acc[i] = (f32x4)(0.f);
    float m_run[4], l_run[4];
    #pragma unroll
    for (int r = 0; r < 4; ++r) { m_run[r] = -1e30f; l_run[r] = 0.f; }

    const int row16 = tid >> 4;        // 0..15 (staging row within pass)
    const int col4  = (tid & 15) * 4;  // 0..60 (staging col)

    for (int s0 = 0; s0 < SK; s0 += NTILE) {
        __syncthreads();   // previous compute done before overwriting tiles
        if (tid < NTILE)
            padv[tid] = mask[b * SK + s0 + tid] ? 0.f : -10000.f;

        #pragma unroll
        for (int pass = 0; pass < 4; ++pass) {
            const int n = pass * 16 + row16;
            const size_t srow = ((size_t)(b * SK + s0 + n) * 2) * (HKV * DD) + hk * DD + col4;
            f32x4 kvec = *(const f32x4*)(kv + srow);
            f32x4 vvec = *(const f32x4*)(kv + srow + HKV * DD);
            bf16x4 kb;
            #pragma unroll
            for (int j = 0; j < 4; ++j) kb[j] = (bf16_t)kvec[j];
            *(bf16x4*)&Ks[n][col4] = kb;
            #pragma unroll
            for (int j = 0; j < 4; ++j) Vt[col4 + j][n] = (bf16_t)vvec[j];
        }
        __syncthreads();   // tiles visible to all waves

        // ---- S = Q K^T  (16 rows x 64 cols per wave) ----
        f32x4 sacc[4];
        #pragma unroll
        for (int nb = 0; nb < 4; ++nb) {
            sacc[nb] = (f32x4)(0.f);
            #pragma unroll
            for (int kk = 0; kk < 2; ++kk) {
                bf16x8 kf = *(const bf16x8*)&Ks[nb * 16 + l16][kk * 32 + lg * 8];
                sacc[nb] = __builtin_amdgcn_mfma_f32_16x16x32_bf16(qf[kk], kf, sacc[nb], 0, 0, 0);
            }
        }

        // ---- mask + online softmax (wave-parallel, per 16-lane col group) ----
        float pv_[4];
        #pragma unroll
        for (int nb = 0; nb < 4; ++nb) pv_[nb] = padv[nb * 16 + l16];

        #pragma unroll
        for (int r = 0; r < 4; ++r) {
            float rmax = -1e30f;
            #pragma unroll
            for (int nb = 0; nb < 4; ++nb) {
                sacc[nb][r] += pv_[nb];
                rmax = fmaxf(rmax, sacc[nb][r]);
            }
            #pragma unroll
            for (int off = 1; off < 16; off <<= 1)
                rmax = fmaxf(rmax, __shfl_xor(rmax, off, 64));
            const float mnew  = fmaxf(m_run[r], rmax);
            const float alpha = __expf(m_run[r] - mnew);
            float ssum = 0.f;
            #pragma unroll
            for (int nb = 0; nb < 4; ++nb) {
                float p = __expf(sacc[nb][r] - mnew);
                sacc[nb][r] = p;
                ssum += p;
            }
            #pragma unroll
            for (int off = 1; off < 16; off <<= 1)
                ssum += __shfl_xor(ssum, off, 64);
            l_run[r] = l_run[r] * alpha + ssum;
            m_run[r] = mnew;
            #pragma unroll
            for (int dc = 0; dc < 4; ++dc) o_acc[dc][r] *= alpha;
        }

        // ---- P -> per-wave LDS (bf16) ----
        #pragma unroll
        for (int nb = 0; nb < 4; ++nb) {
            #pragma unroll
            for (int r = 0; r < 4; ++r)
                Ps[wid][lg * 4 + r][nb * 16 + l16] = (bf16_t)sacc[nb][r];
        }
        asm volatile("s_waitcnt lgkmcnt(0)" ::: "memory");

        // ---- O += P V ----
        #pragma unroll
        for (int ks = 0; ks < 2; ++ks) {
            bf16x8 pa = *(const bf16x8*)&Ps[wid][l16][ks * 32 + lg * 8];
            #pragma unroll
            for (int dc = 0; dc < 4; ++dc) {
                bf16x8 vb = *(const bf16x8*)&Vt[dc * 16 + l16][ks * 32 + lg * 8];
                o_acc[dc] = __builtin_amdgcn_mfma_f32_16x16x32_bf16(pa, vb, o_acc[dc], 0, 0, 0);
            }
        }
    }

    // ---- epilogue: normalize and store f32 ----
    float* op = out + ((size_t)(b * SQ + qrow0) * NH + h) * DD;
    #pragma unroll
    for (int r = 0; r < 4; ++r) {
        const float inv = 1.f / l_run[r];
        const int row = lg * 4 + r;
        #pragma unroll
        for (int dc = 0; dc < 4; ++dc)
            op[(size_t)row * (NH * DD) + dc * 16 + l16] = o_acc[dc][r] * inv;
    }
}

extern "C" void kernel_launch(void* const* d_in, const int* in_sizes, int n_in,
                              void* d_out, int out_size, void* d_ws, size_t ws_size,
                              hipStream_t stream) {
    const float* q    = (const float*)d_in[0];
    const float* kv   = (const float*)d_in[1];
    const int*   mask = (const int*)d_in[2];
    float* out = (float*)d_out;

    const int nblocks = BB * NH * (SQ / MTILE);   // 1024
    fattn_kernel<<<nblocks, 256, 0, stream>>>(q, kv, mask, out);
}

// Round 2
// 91.560 us; speedup vs baseline: 1.8957x; 1.8957x over previous
//
#include <hip/hip_runtime.h>
#include <hip/hip_bf16.h>

typedef __bf16 bf16_t;
typedef bf16_t bf16x8 __attribute__((ext_vector_type(8)));
typedef bf16_t bf16x4 __attribute__((ext_vector_type(4)));
typedef float f32x4 __attribute__((ext_vector_type(4)));
typedef int   i32x4 __attribute__((ext_vector_type(4)));

#define BB 2
#define SQ 2048
#define SK 2048
#define NH 16
#define HKV 4
#define DD 64
#define GQ (NH / HKV)       // 4
#define MTILE 64            // q rows per block (16 per wave)
#define NTILE 64            // kv cols per tile
#define NT (SK / NTILE)     // 32

// LDS tiles: row stride 128 B (64 bf16), XOR swizzle on byte-within-row.
// K / P: rows read by stride-1 lane octets -> swz = (row&7)<<4.
__device__ __forceinline__ int swzK(int row, int colByte) {
    return row * 128 + (colByte ^ ((row & 7) << 4));
}
// V^T: written by d-stride-4 lane octets, read by d-stride-1 octets.
// f(d) = ((d&3)<<1) ^ ((d>>2)&7) is distinct over both octet patterns.
__device__ __forceinline__ int swzV(int d, int colByte) {
    const int f = ((d & 3) << 1) ^ ((d >> 2) & 7);
    return d * 128 + (colByte ^ (f << 4));
}

__global__ __launch_bounds__(256, 4)
void fattn_kernel(const float* __restrict__ q,
                  const float* __restrict__ kv,
                  const int* __restrict__ mask,
                  float* __restrict__ out)
{
    __shared__ __align__(16) bf16_t Ks[2][NTILE * 64];   // [s][k] swzK
    __shared__ __align__(16) bf16_t Vt[2][DD * 64];      // [d][s] swzV
    __shared__ __align__(16) bf16_t Ps[4][16 * 64];      // per-wave [t][s] swzK

    const int tid  = threadIdx.x;
    const int wid  = tid >> 6;
    const int lane = tid & 63;
    const int l16  = lane & 15;
    const int lg   = lane >> 4;        // 0..3

    // XCD-aware bijective swizzle: 1024 wgs, 8 XCDs, 128-wg contiguous chunks.
    const int bid = (blockIdx.x & 7) * 128 + (blockIdx.x >> 3);
    const int qt  = bid & 31;          // bid % (SQ/MTILE)
    const int bh  = bid >> 5;
    const int h   = bh & 15;
    const int b   = bh >> 4;
    const int hk  = h / GQ;

    const int qrow0 = qt * MTILE + wid * 16;
    const float scale = 0.125f;        // 1/sqrt(64)

    // ---- Q fragments (registers, whole kernel). Used as the B operand of
    // the swapped QK^T: b-frag = Q row t=l16, elems k = kk*32+lg*8.. ----
    bf16x8 qf[2];
    {
        const float* qp = q + ((size_t)(b * SQ + qrow0 + l16) * NH + h) * DD;
        #pragma unroll
        for (int kk = 0; kk < 2; ++kk) {
            const int dofs = kk * 32 + lg * 8;
            f32x4 v0 = *(const f32x4*)(qp + dofs);
            f32x4 v1 = *(const f32x4*)(qp + dofs + 4);
            #pragma unroll
            for (int j = 0; j < 4; ++j) {
                qf[kk][j]     = (bf16_t)(v0[j] * scale);
                qf[kk][4 + j] = (bf16_t)(v1[j] * scale);
            }
        }
    }

    // staging assignment: thread owns rows s = s4*4+p (p=0..3), cols d0..d0+3
    const int s4 = tid >> 4;           // 0..15
    const int d0 = (tid & 15) * 4;     // 0..60

    f32x4 kk4[4], vv4[4];
    auto stageLoad = [&](int t) {
        const int s0 = t * NTILE;
        #pragma unroll
        for (int p = 0; p < 4; ++p) {
            const int s = s4 * 4 + p;
            const float* base = kv + (size_t)((b * SK + s0 + s) * 2) * (HKV * DD) + hk * DD + d0;
            kk4[p] = *(const f32x4*)base;
            vv4[p] = *(const f32x4*)(base + HKV * DD);
        }
    };
    auto stageWrite = [&](int buf) {
        #pragma unroll
        for (int p = 0; p < 4; ++p) {
            const int s = s4 * 4 + p;
            bf16x4 kb;
            #pragma unroll
            for (int j = 0; j < 4; ++j) kb[j] = (bf16_t)kk4[p][j];
            *(bf16x4*)((char*)Ks[buf] + swzK(s, d0 * 2)) = kb;
        }
        #pragma unroll
        for (int j = 0; j < 4; ++j) {
            bf16x4 tv;
            #pragma unroll
            for (int p = 0; p < 4; ++p) tv[p] = (bf16_t)vv4[p][j];
            *(bf16x4*)((char*)Vt[buf] + swzV(d0 + j, s4 * 8)) = tv;
        }
    };

    stageLoad(0);
    stageWrite(0);
    __syncthreads();

    f32x4 o_acc[4];
    #pragma unroll
    for (int i = 0; i < 4; ++i) o_acc[i] = (f32x4)(0.f);
    float m_run = -1e30f, l_run = 0.f;   // per-lane: q-row t = l16

    for (int t = 0; t < NT; ++t) {
        const int cur = t & 1;
        if (t + 1 < NT) stageLoad(t + 1);

        // mask pad values for this lane's 16 s-columns (L2-resident, 16B loads)
        f32x4 pad[4];
        #pragma unroll
        for (int nb = 0; nb < 4; ++nb) {
            i32x4 mb = *(const i32x4*)&mask[b * SK + t * NTILE + nb * 16 + lg * 4];
            #pragma unroll
            for (int r = 0; r < 4; ++r) pad[nb][r] = mb[r] ? 0.f : -10000.f;
        }

        // ---- swapped QK^T: S^T[s][t] = K·Q^T ; lane holds s=nb*16+lg*4+r, t=l16
        f32x4 sacc[4];
        #pragma unroll
        for (int nb = 0; nb < 4; ++nb) {
            sacc[nb] = (f32x4)(0.f);
            #pragma unroll
            for (int kk = 0; kk < 2; ++kk) {
                bf16x8 kf = *(const bf16x8*)((char*)Ks[cur] + swzK(nb * 16 + l16, kk * 64 + lg * 16));
                sacc[nb] = __builtin_amdgcn_mfma_f32_16x16x32_bf16(kf, qf[kk], sacc[nb], 0, 0, 0);
            }
        }

        // ---- online softmax for row t=l16 (in-lane 16 + 2 shuffles) ----
        float rmax = -1e30f;
        #pragma unroll
        for (int nb = 0; nb < 4; ++nb) {
            #pragma unroll
            for (int r = 0; r < 4; ++r) {
                sacc[nb][r] += pad[nb][r];
                rmax = fmaxf(rmax, sacc[nb][r]);
            }
        }
        rmax = fmaxf(rmax, __shfl_xor(rmax, 16, 64));
        rmax = fmaxf(rmax, __shfl_xor(rmax, 32, 64));
        const float mnew  = fmaxf(m_run, rmax);
        const float alpha = __expf(m_run - mnew);
        float ssum = 0.f;
        #pragma unroll
        for (int nb = 0; nb < 4; ++nb) {
            #pragma unroll
            for (int r = 0; r < 4; ++r) {
                float p = __expf(sacc[nb][r] - mnew);
                sacc[nb][r] = p;
                ssum += p;
            }
        }
        ssum += __shfl_xor(ssum, 16, 64);
        ssum += __shfl_xor(ssum, 32, 64);
        l_run = l_run * alpha + ssum;
        m_run = mnew;

        // rescale O rows (alpha lives in lane t; o_acc rows are t=lg*4+r)
        #pragma unroll
        for (int r = 0; r < 4; ++r) {
            const float a = __shfl(alpha, lg * 4 + r, 64);
            #pragma unroll
            for (int dc = 0; dc < 4; ++dc) o_acc[dc][r] *= a;
        }

        // ---- P -> per-wave LDS, packed b64 writes ----
        #pragma unroll
        for (int nb = 0; nb < 4; ++nb) {
            bf16x4 pb;
            #pragma unroll
            for (int r = 0; r < 4; ++r) pb[r] = (bf16_t)sacc[nb][r];
            *(bf16x4*)((char*)Ps[wid] + swzK(l16, (nb * 16 + lg * 4) * 2)) = pb;
        }

        // ---- O += P V ----
        #pragma unroll
        for (int ks = 0; ks < 2; ++ks) {
            bf16x8 pa = *(const bf16x8*)((char*)Ps[wid] + swzK(l16, ks * 64 + lg * 16));
            #pragma unroll
            for (int dc = 0; dc < 4; ++dc) {
                bf16x8 vb = *(const bf16x8*)((char*)Vt[cur] + swzV(dc * 16 + l16, ks * 64 + lg * 16));
                o_acc[dc] = __builtin_amdgcn_mfma_f32_16x16x32_bf16(pa, vb, o_acc[dc], 0, 0, 0);
            }
        }

        if (t + 1 < NT) stageWrite(cur ^ 1);
        __syncthreads();
    }

    // ---- epilogue ----
    float* op = out + ((size_t)(b * SQ + qrow0) * NH + h) * DD;
    #pragma unroll
    for (int r = 0; r < 4; ++r) {
        const float linv = 1.f / __shfl(l_run, lg * 4 + r, 64);
        const int row = lg * 4 + r;
        #pragma unroll
        for (int dc = 0; dc < 4; ++dc)
            op[(size_t)row * (NH * DD) + dc * 16 + l16] = o_acc[dc][r] * linv;
    }
}

extern "C" void kernel_launch(void* const* d_in, const int* in_sizes, int n_in,
                              void* d_out, int out_size, void* d_ws, size_t ws_size,
                              hipStream_t stream) {
    const float* q    = (const float*)d_in[0];
    const float* kv   = (const float*)d_in[1];
    const int*   mask = (const int*)d_in[2];
    float* out = (float*)d_out;

    const int nblocks = BB * NH * (SQ / MTILE);   // 1024
    fattn_kernel<<<nblocks, 256, 0, stream>>>(q, kv, mask, out);
}

// Round 3
// 82.867 us; speedup vs baseline: 2.0946x; 1.1049x over previous
//
#include <hip/hip_runtime.h>
#include <hip/hip_bf16.h>
#include <stdint.h>

typedef __bf16 bf16_t;
typedef bf16_t bf16x8 __attribute__((ext_vector_type(8)));
typedef bf16_t bf16x4 __attribute__((ext_vector_type(4)));
typedef float f32x4 __attribute__((ext_vector_type(4)));
typedef int   i32x4 __attribute__((ext_vector_type(4)));

#define BB 2
#define SQ 2048
#define SK 2048
#define NH 16
#define HKV 4
#define DD 64
#define GQ (NH / HKV)       // 4
#define MTILE 64            // q rows per block (16 per wave)
#define NTILE 64            // kv cols per tile
#define NT (SK / NTILE)     // 32

// workspace layout: pre-swizzled bf16 K tiles, V^T tiles, f32 pad array
#define KTILE_BYTES 8192                                  // 64 s x 64 d x 2B
#define KG_SIZE ((size_t)BB * HKV * NT * KTILE_BYTES)     // 2 MB
#define KG_OFF  ((size_t)0)
#define VG_OFF  KG_SIZE
#define PAD_OFF (2 * KG_SIZE)
#define WS_NEED (PAD_OFF + (size_t)BB * SK * 4)

// LDS tiles: row stride 128 B, XOR swizzle on byte-within-row (stays in-row).
__device__ __forceinline__ int swzK(int row, int colByte) {
    return row * 128 + (colByte ^ ((row & 7) << 4));
}
// V^T: written by d-stride-4 lane octets, read by d-stride-1 octets.
__device__ __forceinline__ int swzV(int d, int colByte) {
    const int f = ((d & 3) << 1) ^ ((d >> 2) & 7);
    return d * 128 + (colByte ^ (f << 4));
}

#define GLDS(g, l) __builtin_amdgcn_global_load_lds( \
    (const __attribute__((address_space(1))) void*)(g), \
    (__attribute__((address_space(3))) void*)(l), 16, 0, 0)

// ---------------- pre-pass: convert + transpose + bake swizzle ----------------
__global__ __launch_bounds__(256)
void prep_kernel(const float* __restrict__ kv, const int* __restrict__ mask,
                 char* __restrict__ ws)
{
    const int bid  = blockIdx.x;           // [b][hk][tile]
    const int tile = bid & 31;
    const int bh   = bid >> 5;
    const int hk   = bh & 3;
    const int b    = bh >> 2;
    const int tid  = threadIdx.x;
    const int s4   = tid >> 4;             // 0..15
    const int d0   = (tid & 15) * 4;       // 0..60

    bf16_t* Kt = (bf16_t*)(ws + KG_OFF + (size_t)bid * KTILE_BYTES);
    bf16_t* Vt = (bf16_t*)(ws + VG_OFF + (size_t)bid * KTILE_BYTES);

    f32x4 kk4[4], vv4[4];
    #pragma unroll
    for (int p = 0; p < 4; ++p) {
        const int s = s4 * 4 + p;
        const float* base = kv + (size_t)((b * SK + tile * NTILE + s) * 2) * (HKV * DD) + hk * DD + d0;
        kk4[p] = *(const f32x4*)base;
        vv4[p] = *(const f32x4*)(base + HKV * DD);
    }
    #pragma unroll
    for (int p = 0; p < 4; ++p) {
        bf16x4 kb;
        #pragma unroll
        for (int j = 0; j < 4; ++j) kb[j] = (bf16_t)kk4[p][j];
        *(bf16x4*)((char*)Kt + swzK(s4 * 4 + p, d0 * 2)) = kb;
    }
    #pragma unroll
    for (int j = 0; j < 4; ++j) {
        bf16x4 tv;
        #pragma unroll
        for (int p = 0; p < 4; ++p) tv[p] = (bf16_t)vv4[p][j];
        *(bf16x4*)((char*)Vt + swzV(d0 + j, s4 * 8)) = tv;
    }
    if (hk == 0 && tid < NTILE) {
        const int s = tile * NTILE + tid;
        ((float*)(ws + PAD_OFF))[b * SK + s] = mask[b * SK + s] ? 0.f : -10000.f;
    }
}

// ---------------- main kernel: global_load_lds staging ----------------
__global__ __launch_bounds__(256, 4)
void fattn_pre(const float* __restrict__ q, const char* __restrict__ ws,
               float* __restrict__ out)
{
    __shared__ __align__(16) bf16_t Ks[2][NTILE * 64];   // swizzled image
    __shared__ __align__(16) bf16_t Vs[2][DD * 64];      // swizzled image
    __shared__ __align__(16) bf16_t Ps[4][16 * 64];      // per-wave P, swzK

    const int tid  = threadIdx.x;
    const int wid  = tid >> 6;
    const int lane = tid & 63;
    const int l16  = lane & 15;
    const int lg   = lane >> 4;

    // XCD-aware bijective swizzle: 1024 wgs, 8 XCDs, 128-wg chunks
    const int bid = (blockIdx.x & 7) * 128 + (blockIdx.x >> 3);
    const int qt  = bid & 31;
    const int bh  = bid >> 5;
    const int h   = bh & 15;
    const int b   = bh >> 4;
    const int hk  = h / GQ;

    const int qrow0 = qt * MTILE + wid * 16;
    const float scale = 0.125f;

    // Q fragments (B operand of swapped QK^T), scale folded in
    bf16x8 qf[2];
    {
        const float* qp = q + ((size_t)(b * SQ + qrow0 + l16) * NH + h) * DD;
        #pragma unroll
        for (int kk = 0; kk < 2; ++kk) {
            const int dofs = kk * 32 + lg * 8;
            f32x4 v0 = *(const f32x4*)(qp + dofs);
            f32x4 v1 = *(const f32x4*)(qp + dofs + 4);
            #pragma unroll
            for (int j = 0; j < 4; ++j) {
                qf[kk][j]     = (bf16_t)(v0[j] * scale);
                qf[kk][4 + j] = (bf16_t)(v1[j] * scale);
            }
        }
    }

    const char* kgb = ws + KG_OFF + (size_t)((b * HKV + hk) * NT) * KTILE_BYTES;
    const char* vgb = ws + VG_OFF + (size_t)((b * HKV + hk) * NT) * KTILE_BYTES;
    const float* padb = (const float*)(ws + PAD_OFF) + b * SK;

    auto STAGE = [&](int t, int buf) {
        const char* ksrc = kgb + (size_t)t * KTILE_BYTES + wid * 2048 + lane * 16;
        const char* vsrc = vgb + (size_t)t * KTILE_BYTES + wid * 2048 + lane * 16;
        char* kdst = (char*)Ks[buf] + wid * 2048;   // wave-uniform base
        char* vdst = (char*)Vs[buf] + wid * 2048;
        GLDS(ksrc, kdst);
        GLDS(ksrc + 1024, kdst + 1024);
        GLDS(vsrc, vdst);
        GLDS(vsrc + 1024, vdst + 1024);
    };

    STAGE(0, 0);
    __syncthreads();   // drains vmcnt before barrier

    f32x4 o_acc[4];
    #pragma unroll
    for (int i = 0; i < 4; ++i) o_acc[i] = (f32x4)(0.f);
    float m_run = -1e30f, l_run = 0.f;    // per-lane q-row t = l16

    for (int t = 0; t < NT; ++t) {
        const int cur = t & 1;
        if (t + 1 < NT) STAGE(t + 1, cur ^ 1);

        // pad values for this lane's 16 s-columns (L2-resident f32)
        f32x4 pad[4];
        #pragma unroll
        for (int nb = 0; nb < 4; ++nb)
            pad[nb] = *(const f32x4*)(padb + t * NTILE + nb * 16 + lg * 4);

        // swapped QK^T: S^T = K·Q^T ; lane holds s = nb*16+lg*4+r, t = l16
        f32x4 sacc[4];
        __builtin_amdgcn_s_setprio(1);
        #pragma unroll
        for (int nb = 0; nb < 4; ++nb) {
            sacc[nb] = (f32x4)(0.f);
            #pragma unroll
            for (int kk = 0; kk < 2; ++kk) {
                bf16x8 kf = *(const bf16x8*)((char*)Ks[cur] + swzK(nb * 16 + l16, kk * 64 + lg * 16));
                sacc[nb] = __builtin_amdgcn_mfma_f32_16x16x32_bf16(kf, qf[kk], sacc[nb], 0, 0, 0);
            }
        }
        __builtin_amdgcn_s_setprio(0);

        // online softmax for row t=l16 (in-lane + 2 shuffles)
        float rmax = -1e30f;
        #pragma unroll
        for (int nb = 0; nb < 4; ++nb) {
            #pragma unroll
            for (int r = 0; r < 4; ++r) {
                sacc[nb][r] += pad[nb][r];
                rmax = fmaxf(rmax, sacc[nb][r]);
            }
        }
        rmax = fmaxf(rmax, __shfl_xor(rmax, 16, 64));
        rmax = fmaxf(rmax, __shfl_xor(rmax, 32, 64));
        const float mnew  = fmaxf(m_run, rmax);
        const float alpha = __expf(m_run - mnew);
        float ssum = 0.f;
        #pragma unroll
        for (int nb = 0; nb < 4; ++nb) {
            #pragma unroll
            for (int r = 0; r < 4; ++r) {
                float p = __expf(sacc[nb][r] - mnew);
                sacc[nb][r] = p;
                ssum += p;
            }
        }
        ssum += __shfl_xor(ssum, 16, 64);
        ssum += __shfl_xor(ssum, 32, 64);
        l_run = l_run * alpha + ssum;
        m_run = mnew;

        // rescale O rows (alpha lives in lane t; o_acc rows are t=lg*4+r)
        #pragma unroll
        for (int r = 0; r < 4; ++r) {
            const float a = __shfl(alpha, lg * 4 + r, 64);
            #pragma unroll
            for (int dc = 0; dc < 4; ++dc) o_acc[dc][r] *= a;
        }

        // P -> per-wave LDS (packed b64 writes)
        #pragma unroll
        for (int nb = 0; nb < 4; ++nb) {
            bf16x4 pb;
            #pragma unroll
            for (int r = 0; r < 4; ++r) pb[r] = (bf16_t)sacc[nb][r];
            *(bf16x4*)((char*)Ps[wid] + swzK(l16, (nb * 16 + lg * 4) * 2)) = pb;
        }
        asm volatile("s_waitcnt lgkmcnt(0)" ::: "memory");

        // O += P V
        __builtin_amdgcn_s_setprio(1);
        #pragma unroll
        for (int ks = 0; ks < 2; ++ks) {
            bf16x8 pa = *(const bf16x8*)((char*)Ps[wid] + swzK(l16, ks * 64 + lg * 16));
            #pragma unroll
            for (int dc = 0; dc < 4; ++dc) {
                bf16x8 vb = *(const bf16x8*)((char*)Vs[cur] + swzV(dc * 16 + l16, ks * 64 + lg * 16));
                o_acc[dc] = __builtin_amdgcn_mfma_f32_16x16x32_bf16(pa, vb, o_acc[dc], 0, 0, 0);
            }
        }
        __builtin_amdgcn_s_setprio(0);

        __syncthreads();   // next tile staged + all reads of cur done
    }

    float* op = out + ((size_t)(b * SQ + qrow0) * NH + h) * DD;
    #pragma unroll
    for (int r = 0; r < 4; ++r) {
        const float linv = 1.f / __shfl(l_run, lg * 4 + r, 64);
        const int row = lg * 4 + r;
        #pragma unroll
        for (int dc = 0; dc < 4; ++dc)
            op[(size_t)row * (NH * DD) + dc * 16 + l16] = o_acc[dc][r] * linv;
    }
}

// ---------------- fallback (round-2 monolithic) if ws too small ----------------
__global__ __launch_bounds__(256, 4)
void fattn_fb(const float* __restrict__ q, const float* __restrict__ kv,
              const int* __restrict__ mask, float* __restrict__ out)
{
    __shared__ __align__(16) bf16_t Ks[2][NTILE * 64];
    __shared__ __align__(16) bf16_t Vt[2][DD * 64];
    __shared__ __align__(16) bf16_t Ps[4][16 * 64];

    const int tid  = threadIdx.x;
    const int wid  = tid >> 6;
    const int lane = tid & 63;
    const int l16  = lane & 15;
    const int lg   = lane >> 4;

    const int bid = (blockIdx.x & 7) * 128 + (blockIdx.x >> 3);
    const int qt  = bid & 31;
    const int bh  = bid >> 5;
    const int h   = bh & 15;
    const int b   = bh >> 4;
    const int hk  = h / GQ;

    const int qrow0 = qt * MTILE + wid * 16;
    const float scale = 0.125f;

    bf16x8 qf[2];
    {
        const float* qp = q + ((size_t)(b * SQ + qrow0 + l16) * NH + h) * DD;
        #pragma unroll
        for (int kk = 0; kk < 2; ++kk) {
            const int dofs = kk * 32 + lg * 8;
            f32x4 v0 = *(const f32x4*)(qp + dofs);
            f32x4 v1 = *(const f32x4*)(qp + dofs + 4);
            #pragma unroll
            for (int j = 0; j < 4; ++j) {
                qf[kk][j]     = (bf16_t)(v0[j] * scale);
                qf[kk][4 + j] = (bf16_t)(v1[j] * scale);
            }
        }
    }

    const int s4 = tid >> 4;
    const int d0 = (tid & 15) * 4;

    f32x4 kk4[4], vv4[4];
    auto stageLoad = [&](int t) {
        const int s0 = t * NTILE;
        #pragma unroll
        for (int p = 0; p < 4; ++p) {
            const int s = s4 * 4 + p;
            const float* base = kv + (size_t)((b * SK + s0 + s) * 2) * (HKV * DD) + hk * DD + d0;
            kk4[p] = *(const f32x4*)base;
            vv4[p] = *(const f32x4*)(base + HKV * DD);
        }
    };
    auto stageWrite = [&](int buf) {
        #pragma unroll
        for (int p = 0; p < 4; ++p) {
            bf16x4 kb;
            #pragma unroll
            for (int j = 0; j < 4; ++j) kb[j] = (bf16_t)kk4[p][j];
            *(bf16x4*)((char*)Ks[buf] + swzK(s4 * 4 + p, d0 * 2)) = kb;
        }
        #pragma unroll
        for (int j = 0; j < 4; ++j) {
            bf16x4 tv;
            #pragma unroll
            for (int p = 0; p < 4; ++p) tv[p] = (bf16_t)vv4[p][j];
            *(bf16x4*)((char*)Vt[buf] + swzV(d0 + j, s4 * 8)) = tv;
        }
    };

    stageLoad(0);
    stageWrite(0);
    __syncthreads();

    f32x4 o_acc[4];
    #pragma unroll
    for (int i = 0; i < 4; ++i) o_acc[i] = (f32x4)(0.f);
    float m_run = -1e30f, l_run = 0.f;

    for (int t = 0; t < NT; ++t) {
        const int cur = t & 1;
        if (t + 1 < NT) stageLoad(t + 1);

        f32x4 pad[4];
        #pragma unroll
        for (int nb = 0; nb < 4; ++nb) {
            i32x4 mb = *(const i32x4*)&mask[b * SK + t * NTILE + nb * 16 + lg * 4];
            #pragma unroll
            for (int r = 0; r < 4; ++r) pad[nb][r] = mb[r] ? 0.f : -10000.f;
        }

        f32x4 sacc[4];
        #pragma unroll
        for (int nb = 0; nb < 4; ++nb) {
            sacc[nb] = (f32x4)(0.f);
            #pragma unroll
            for (int kk = 0; kk < 2; ++kk) {
                bf16x8 kf = *(const bf16x8*)((char*)Ks[cur] + swzK(nb * 16 + l16, kk * 64 + lg * 16));
                sacc[nb] = __builtin_amdgcn_mfma_f32_16x16x32_bf16(kf, qf[kk], sacc[nb], 0, 0, 0);
            }
        }

        float rmax = -1e30f;
        #pragma unroll
        for (int nb = 0; nb < 4; ++nb) {
            #pragma unroll
            for (int r = 0; r < 4; ++r) {
                sacc[nb][r] += pad[nb][r];
                rmax = fmaxf(rmax, sacc[nb][r]);
            }
        }
        rmax = fmaxf(rmax, __shfl_xor(rmax, 16, 64));
        rmax = fmaxf(rmax, __shfl_xor(rmax, 32, 64));
        const float mnew  = fmaxf(m_run, rmax);
        const float alpha = __expf(m_run - mnew);
        float ssum = 0.f;
        #pragma unroll
        for (int nb = 0; nb < 4; ++nb) {
            #pragma unroll
            for (int r = 0; r < 4; ++r) {
                float p = __expf(sacc[nb][r] - mnew);
                sacc[nb][r] = p;
                ssum += p;
            }
        }
        ssum += __shfl_xor(ssum, 16, 64);
        ssum += __shfl_xor(ssum, 32, 64);
        l_run = l_run * alpha + ssum;
        m_run = mnew;

        #pragma unroll
        for (int r = 0; r < 4; ++r) {
            const float a = __shfl(alpha, lg * 4 + r, 64);
            #pragma unroll
            for (int dc = 0; dc < 4; ++dc) o_acc[dc][r] *= a;
        }

        #pragma unroll
        for (int nb = 0; nb < 4; ++nb) {
            bf16x4 pb;
            #pragma unroll
            for (int r = 0; r < 4; ++r) pb[r] = (bf16_t)sacc[nb][r];
            *(bf16x4*)((char*)Ps[wid] + swzK(l16, (nb * 16 + lg * 4) * 2)) = pb;
        }
        asm volatile("s_waitcnt lgkmcnt(0)" ::: "memory");

        #pragma unroll
        for (int ks = 0; ks < 2; ++ks) {
            bf16x8 pa = *(const bf16x8*)((char*)Ps[wid] + swzK(l16, ks * 64 + lg * 16));
            #pragma unroll
            for (int dc = 0; dc < 4; ++dc) {
                bf16x8 vb = *(const bf16x8*)((char*)Vt[cur] + swzV(dc * 16 + l16, ks * 64 + lg * 16));
                o_acc[dc] = __builtin_amdgcn_mfma_f32_16x16x32_bf16(pa, vb, o_acc[dc], 0, 0, 0);
            }
        }

        if (t + 1 < NT) stageWrite(cur ^ 1);
        __syncthreads();
    }

    float* op = out + ((size_t)(b * SQ + qrow0) * NH + h) * DD;
    #pragma unroll
    for (int r = 0; r < 4; ++r) {
        const float linv = 1.f / __shfl(l_run, lg * 4 + r, 64);
        const int row = lg * 4 + r;
        #pragma unroll
        for (int dc = 0; dc < 4; ++dc)
            op[(size_t)row * (NH * DD) + dc * 16 + l16] = o_acc[dc][r] * linv;
    }
}

extern "C" void kernel_launch(void* const* d_in, const int* in_sizes, int n_in,
                              void* d_out, int out_size, void* d_ws, size_t ws_size,
                              hipStream_t stream) {
    const float* q    = (const float*)d_in[0];
    const float* kv   = (const float*)d_in[1];
    const int*   mask = (const int*)d_in[2];
    float* out = (float*)d_out;

    const int nblocks = BB * NH * (SQ / MTILE);   // 1024
    if (ws_size >= WS_NEED) {
        prep_kernel<<<BB * HKV * NT, 256, 0, stream>>>(kv, mask, (char*)d_ws);
        fattn_pre<<<nblocks, 256, 0, stream>>>(q, (const char*)d_ws, out);
    } else {
        fattn_fb<<<nblocks, 256, 0, stream>>>(q, kv, mask, out);
    }
}

// Round 4
// 62.122 us; speedup vs baseline: 2.7941x; 1.3339x over previous
//
#include <hip/hip_runtime.h>
#include <hip/hip_bf16.h>
#include <stdint.h>

typedef __bf16 bf16_t;
typedef bf16_t bf16x8 __attribute__((ext_vector_type(8)));
typedef bf16_t bf16x4 __attribute__((ext_vector_type(4)));
typedef float f32x4 __attribute__((ext_vector_type(4)));
typedef float f32x16 __attribute__((ext_vector_type(16)));
typedef uint32_t u32x4 __attribute__((ext_vector_type(4)));

#define BB 2
#define SQ 2048
#define SK 2048
#define NH 16
#define HKV 4
#define DD 64
#define GQ 4
#define MTILE 128           // q rows per block (32 per wave, 4 waves)
#define NTILE 64
#define NT (SK / NTILE)     // 32

#define KTILE_BYTES 8192
#define KG_SIZE ((size_t)BB * HKV * NT * KTILE_BYTES)   // 2 MB
#define KG_OFF  ((size_t)0)
#define VG_OFF  KG_SIZE
#define PAD_OFF (2 * KG_SIZE)
#define WS_NEED (PAD_OFF + (size_t)BB * SK * 4)

// 128B rows, XOR swizzle within row (16B granule). Read pattern: 32 rows x 2
// 16B slots per instr -> inherent-minimum bank usage for ds_read_b128.
__device__ __forceinline__ int swzK(int row, int colByte) {
    return row * 128 + (colByte ^ ((row & 7) << 4));
}

#define GLDS(g, l) __builtin_amdgcn_global_load_lds( \
    (const __attribute__((address_space(1))) void*)(g), \
    (__attribute__((address_space(3))) void*)(l), 16, 0, 0)

// ---------------- pre-pass: f32->bf16, transpose V, bake swizzle, pad array --
__global__ __launch_bounds__(256)
void prep_kernel(const float* __restrict__ kv, const int* __restrict__ mask,
                 char* __restrict__ ws)
{
    const int bid  = blockIdx.x;           // [b][hk][tile]
    const int tile = bid & 31;
    const int bh   = bid >> 5;
    const int hk   = bh & 3;
    const int b    = bh >> 2;
    const int tid  = threadIdx.x;
    const int s4   = tid >> 4;             // 0..15
    const int d0   = (tid & 15) * 4;       // 0..60

    bf16_t* Kt = (bf16_t*)(ws + KG_OFF + (size_t)bid * KTILE_BYTES);
    bf16_t* Vt = (bf16_t*)(ws + VG_OFF + (size_t)bid * KTILE_BYTES);

    f32x4 kk4[4], vv4[4];
    #pragma unroll
    for (int p = 0; p < 4; ++p) {
        const int s = s4 * 4 + p;
        const float* base = kv + (size_t)((b * SK + tile * NTILE + s) * 2) * (HKV * DD) + hk * DD + d0;
        kk4[p] = *(const f32x4*)base;
        vv4[p] = *(const f32x4*)(base + HKV * DD);
    }
    #pragma unroll
    for (int p = 0; p < 4; ++p) {
        bf16x4 kb;
        #pragma unroll
        for (int j = 0; j < 4; ++j) kb[j] = (bf16_t)kk4[p][j];
        *(bf16x4*)((char*)Kt + swzK(s4 * 4 + p, d0 * 2)) = kb;
    }
    #pragma unroll
    for (int j = 0; j < 4; ++j) {
        bf16x4 tv;
        #pragma unroll
        for (int p = 0; p < 4; ++p) tv[p] = (bf16_t)vv4[p][j];
        *(bf16x4*)((char*)Vt + swzK(d0 + j, s4 * 8)) = tv;   // V^T rows d
    }
    if (hk == 0 && tid < NTILE) {
        const int s = tile * NTILE + tid;
        // exp2-domain pad: 0 (keep) or -30000 (exp2 -> 0)
        ((float*)(ws + PAD_OFF))[b * SK + s] = mask[b * SK + s] ? 0.f : -30000.f;
    }
}

// ---------------- main: 32x32 MFMA, in-register P, no-max softmax -----------
__global__ __launch_bounds__(256, 2)
void fattn32(const float* __restrict__ q, const char* __restrict__ ws,
             float* __restrict__ out)
{
    __shared__ __align__(16) bf16_t Ks[2][NTILE * 64];   // [s][k] swizzled
    __shared__ __align__(16) bf16_t Vs[2][DD * 64];      // [d][s] swizzled
    __shared__ __align__(16) float  padl[SK / 1];        // 2048 f32 = 8KB? no:
    // NOTE: only this block's b is needed: 2048 floats = 8KB
    const int tid  = threadIdx.x;
    const int wid  = tid >> 6;
    const int lane = tid & 63;
    const int l31  = lane & 31;
    const int hf   = lane >> 5;            // 0/1
    const int ef   = lane & 7;

    // XCD-aware swizzle: 512 wgs, 8 XCDs, 64-wg chunks (one (b,hk) KV slab/XCD)
    const int bid = (blockIdx.x & 7) * 64 + (blockIdx.x >> 3);
    const int qt  = bid & 15;
    const int bh  = bid >> 4;
    const int hq  = bh & 15;
    const int b   = bh >> 4;
    const int hk  = hq / GQ;

    const int qrow0 = qt * MTILE + wid * 32;
    const float SC = 0.18033688011112042f;   // 0.125 * log2(e)

    // Q frags: B-operand of swapped QK^T. lane: t=l31, k = kblk*16 + hf*8 + j
    bf16x8 qf[4];
    {
        const float* qp = q + ((size_t)(b * SQ + qrow0 + l31) * NH + hq) * DD;
        #pragma unroll
        for (int kblk = 0; kblk < 4; ++kblk) {
            f32x4 v0 = *(const f32x4*)(qp + kblk * 16 + hf * 8);
            f32x4 v1 = *(const f32x4*)(qp + kblk * 16 + hf * 8 + 4);
            #pragma unroll
            for (int j = 0; j < 4; ++j) {
                qf[kblk][j]     = (bf16_t)(v0[j] * SC);
                qf[kblk][4 + j] = (bf16_t)(v1[j] * SC);
            }
        }
    }

    const char* kgb = ws + KG_OFF + (size_t)((b * HKV + hk) * NT) * KTILE_BYTES;
    const char* vgb = ws + VG_OFF + (size_t)((b * HKV + hk) * NT) * KTILE_BYTES;
    const float* padg = (const float*)(ws + PAD_OFF) + b * SK;

    auto STAGE = [&](int t, int buf) {
        const char* ksrc = kgb + (size_t)t * KTILE_BYTES + wid * 2048 + lane * 16;
        const char* vsrc = vgb + (size_t)t * KTILE_BYTES + wid * 2048 + lane * 16;
        char* kdst = (char*)Ks[buf] + wid * 2048;
        char* vdst = (char*)Vs[buf] + wid * 2048;
        GLDS(ksrc, kdst);
        GLDS(ksrc + 1024, kdst + 1024);
        GLDS(vsrc, vdst);
        GLDS(vsrc + 1024, vdst + 1024);
    };

    // stage pad array (8KB) once + first K/V tile
    GLDS((const char*)padg + wid * 2048 + lane * 16, (char*)padl + wid * 2048);
    GLDS((const char*)padg + wid * 2048 + 1024 + lane * 16, (char*)padl + wid * 2048 + 1024);
    STAGE(0, 0);
    __syncthreads();

    // LDS read column offsets (loop-invariant)
    int colX[4];
    #pragma unroll
    for (int kblk = 0; kblk < 4; ++kblk)
        colX[kblk] = (kblk * 32 + hf * 16) ^ (ef << 4);

    bf16x8 onesf;
    #pragma unroll
    for (int j = 0; j < 8; ++j) onesf[j] = (bf16_t)1.0f;

    f32x16 o0, o1, osum;
    #pragma unroll
    for (int i = 0; i < 16; ++i) { o0[i] = 0.f; o1[i] = 0.f; osum[i] = 0.f; }
    float m_run = 0.f;
    bool everR = false;

    for (int t = 0; t < NT; ++t) {
        const int cur = t & 1;
        if (t + 1 < NT) STAGE(t + 1, cur ^ 1);

        // ---- init S accumulators with pad (free masking), C-layout:
        // lane col t=l31, row s_local = (r&3) + 8*(r>>2) + 4*hf (+32*sblk)
        f32x16 s0, s1;
        #pragma unroll
        for (int a = 0; a < 4; ++a) {
            f32x4 p0 = *(const f32x4*)&padl[t * 64 + a * 8 + hf * 4];
            f32x4 p1 = *(const f32x4*)&padl[t * 64 + 32 + a * 8 + hf * 4];
            if (everR) {
                #pragma unroll
                for (int c = 0; c < 4; ++c) { p0[c] -= m_run; p1[c] -= m_run; }
            }
            #pragma unroll
            for (int c = 0; c < 4; ++c) { s0[a * 4 + c] = p0[c]; s1[a * 4 + c] = p1[c]; }
        }

        // ---- QK^T (swapped): S^T[s][t] = K·Q^T
        __builtin_amdgcn_s_setprio(1);
        #pragma unroll
        for (int kblk = 0; kblk < 4; ++kblk) {
            bf16x8 kf0 = *(const bf16x8*)((char*)Ks[cur] + l31 * 128 + colX[kblk]);
            bf16x8 kf1 = *(const bf16x8*)((char*)Ks[cur] + 4096 + l31 * 128 + colX[kblk]);
            s0 = __builtin_amdgcn_mfma_f32_32x32x16_bf16(kf0, qf[kblk], s0, 0, 0, 0);
            s1 = __builtin_amdgcn_mfma_f32_32x32x16_bf16(kf1, qf[kblk], s1, 0, 0, 0);
        }
        __builtin_amdgcn_s_setprio(0);

        // ---- safety check (T13 defer): rescale only if scores leave [.,20]
        f32x16 mx;
        #pragma unroll
        for (int i = 0; i < 16; ++i) mx[i] = fmaxf(s0[i], s1[i]);
        #pragma unroll
        for (int off = 8; off > 0; off >>= 1) {
            #pragma unroll
            for (int i = 0; i < 8; ++i)
                if (i < off) mx[i] = fmaxf(mx[i], mx[i + off]);
        }
        const float rmax = mx[0];
        if (__any(rmax > 20.f)) {
            // rare path: shift domain by delta, rescale O and sums
            float rm2 = fmaxf(rmax, __shfl_xor(rmax, 32, 64));
            float delta = fmaxf(rm2, 0.f);
            #pragma unroll
            for (int i = 0; i < 16; ++i) { s0[i] -= delta; s1[i] -= delta; }
            float al = __builtin_amdgcn_exp2f(-delta);
            #pragma unroll
            for (int r = 0; r < 16; ++r) {
                const int t_r = (r & 3) + 8 * (r >> 2) + 4 * hf;
                float ar = __shfl(al, t_r + (lane & 32), 64);
                o0[r] *= ar; o1[r] *= ar; osum[r] *= ar;
            }
            m_run += delta;
            everR = true;
        }

        // ---- P = exp2(S) in place
        #pragma unroll
        for (int i = 0; i < 16; ++i) {
            s0[i] = __builtin_amdgcn_exp2f(s0[i]);
            s1[i] = __builtin_amdgcn_exp2f(s1[i]);
        }

        // ---- P -> A-frag entirely in registers (cvt_pk + permlane32_swap)
        bf16x8 paw[4];
        #pragma unroll
        for (int ks2 = 0; ks2 < 4; ++ks2) {
            const int aX = (ks2 & 1) * 2;
            uint32_t X0, X1, Y0, Y1;
            #define CVTPK(dst, lo, hi) asm("v_cvt_pk_bf16_f32 %0, %1, %2" : "=v"(dst) : "v"(lo), "v"(hi))
            if (ks2 & 2) {
                CVTPK(X0, s1[4*aX + 0], s1[4*aX + 1]);
                CVTPK(X1, s1[4*aX + 2], s1[4*aX + 3]);
                CVTPK(Y0, s1[4*aX + 4], s1[4*aX + 5]);
                CVTPK(Y1, s1[4*aX + 6], s1[4*aX + 7]);
            } else {
                CVTPK(X0, s0[4*aX + 0], s0[4*aX + 1]);
                CVTPK(X1, s0[4*aX + 2], s0[4*aX + 3]);
                CVTPK(Y0, s0[4*aX + 4], s0[4*aX + 5]);
                CVTPK(Y1, s0[4*aX + 6], s0[4*aX + 7]);
            }
            #undef CVTPK
            // vdst.upper <-> vsrc.lower: X' = [X.low | Y.low], Y' = [X.up | Y.up]
            asm("v_permlane32_swap_b32 %0, %1" : "+v"(X0), "+v"(Y0));
            asm("v_permlane32_swap_b32 %0, %1" : "+v"(X1), "+v"(Y1));
            union { u32x4 w; bf16x8 v; } u;
            u.w[0] = X0; u.w[1] = X1; u.w[2] = Y0; u.w[3] = Y1;
            paw[ks2] = u.v;
        }

        // ---- O += P V ; row-sums via ones-MFMA (O-layout, no shuffles)
        __builtin_amdgcn_s_setprio(1);
        #pragma unroll
        for (int ks2 = 0; ks2 < 4; ++ks2) {
            bf16x8 vf0 = *(const bf16x8*)((char*)Vs[cur] + l31 * 128 + colX[ks2]);
            bf16x8 vf1 = *(const bf16x8*)((char*)Vs[cur] + 4096 + l31 * 128 + colX[ks2]);
            o0   = __builtin_amdgcn_mfma_f32_32x32x16_bf16(paw[ks2], vf0, o0, 0, 0, 0);
            o1   = __builtin_amdgcn_mfma_f32_32x32x16_bf16(paw[ks2], vf1, o1, 0, 0, 0);
            osum = __builtin_amdgcn_mfma_f32_32x32x16_bf16(paw[ks2], onesf, osum, 0, 0, 0);
        }
        __builtin_amdgcn_s_setprio(0);

        __syncthreads();
    }

    // ---- epilogue: O-layout lane holds d = nblk*32 + l31, rows t_r
    #pragma unroll
    for (int r = 0; r < 16; ++r) {
        const int t_r = (r & 3) + 8 * (r >> 2) + 4 * hf;
        const float sden = osum[r];
        const float linv = sden > 0.f ? 1.f / sden : 0.f;
        float* op = out + ((size_t)(b * SQ + qrow0 + t_r) * NH + hq) * DD + l31;
        op[0]  = o0[r] * linv;
        op[32] = o1[r] * linv;
    }
}

extern "C" void kernel_launch(void* const* d_in, const int* in_sizes, int n_in,
                              void* d_out, int out_size, void* d_ws, size_t ws_size,
                              hipStream_t stream) {
    const float* q    = (const float*)d_in[0];
    const float* kv   = (const float*)d_in[1];
    const int*   mask = (const int*)d_in[2];
    float* out = (float*)d_out;

    prep_kernel<<<BB * HKV * NT, 256, 0, stream>>>(kv, mask, (char*)d_ws);
    fattn32<<<BB * NH * (SQ / MTILE), 256, 0, stream>>>(q, (const char*)d_ws, out);
}

// Round 5
// 43.607 us; speedup vs baseline: 3.9804x; 1.4246x over previous
//
#include <hip/hip_runtime.h>
#include <hip/hip_bf16.h>
#include <stdint.h>

typedef __bf16 bf16_t;
typedef bf16_t bf16x8 __attribute__((ext_vector_type(8)));
typedef bf16_t bf16x4 __attribute__((ext_vector_type(4)));
typedef float f32x4 __attribute__((ext_vector_type(4)));
typedef float f32x16 __attribute__((ext_vector_type(16)));
typedef uint32_t u32x4 __attribute__((ext_vector_type(4)));
typedef int   i32x4 __attribute__((ext_vector_type(4)));

#define BB 2
#define SQ 2048
#define SK 2048
#define NH 16
#define HKV 4
#define DD 64
#define GQ 4
#define MTILE 128           // q rows per block (32 per wave, 4 waves)
#define NTILE 64
#define MAXNT 32

#define KTILE_BYTES 8192
#define CNT_OFF   ((size_t)0)
#define CIDX_OFF  ((size_t)1024)
#define PADC_OFF  (CIDX_OFF + (size_t)BB * SK * 4)
#define KC_OFF    ((size_t)65536)
#define VC_OFF    (KC_OFF + (size_t)BB * HKV * MAXNT * KTILE_BYTES)

// 128B rows, XOR swizzle within row (16B granule)
__device__ __forceinline__ int swzK(int row, int colByte) {
    return row * 128 + (colByte ^ ((row & 7) << 4));
}

#define GLDS(g, l) __builtin_amdgcn_global_load_lds( \
    (const __attribute__((address_space(1))) void*)(g), \
    (__attribute__((address_space(3))) void*)(l), 16, 0, 0)

// ---------------- pass 1: per-b mask scan -> compacted index list ------------
__global__ __launch_bounds__(256)
void scan_kernel(const int* __restrict__ mask, char* __restrict__ ws)
{
    __shared__ int wtot[4];
    const int b    = blockIdx.x;
    const int tid  = threadIdx.x;
    const int lane = tid & 63;
    const int wid  = tid >> 6;

    int m[8], c = 0;
    {
        const int base = b * SK + tid * 8;
        i32x4 a0 = *(const i32x4*)&mask[base];
        i32x4 a1 = *(const i32x4*)&mask[base + 4];
        #pragma unroll
        for (int j = 0; j < 4; ++j) { m[j] = a0[j] ? 1 : 0; c += m[j]; }
        #pragma unroll
        for (int j = 0; j < 4; ++j) { m[4 + j] = a1[j] ? 1 : 0; c += m[4 + j]; }
    }
    // inclusive wave scan of c
    int sc = c;
    #pragma unroll
    for (int off = 1; off < 64; off <<= 1) {
        int n = __shfl_up(sc, off, 64);
        if (lane >= off) sc += n;
    }
    if (lane == 63) wtot[wid] = sc;
    __syncthreads();
    int wbase = 0;
    #pragma unroll
    for (int w = 0; w < 4; ++w) if (w < wid) wbase += wtot[w];
    const int total = wtot[0] + wtot[1] + wtot[2] + wtot[3];

    int* cidx = (int*)(ws + CIDX_OFF) + b * SK;
    int pos = wbase + sc - c;      // exclusive prefix
    #pragma unroll
    for (int j = 0; j < 8; ++j)
        if (m[j]) cidx[pos++] = tid * 8 + j;

    if (tid == 0) ((int*)(ws + CNT_OFF))[b] = total;

    float* padc = (float*)(ws + PADC_OFF) + b * SK;
    for (int i = tid; i < SK; i += 256)
        padc[i] = (i < total) ? 0.f : -30000.f;
}

// ---------------- pass 2: gather + f32->bf16 + transpose V + bake swizzle ----
__global__ __launch_bounds__(256)
void gather_kernel(const float* __restrict__ kv, char* __restrict__ ws)
{
    const int bid  = blockIdx.x;           // [b][hk][tile]
    const int tile = bid & 31;
    const int bh   = bid >> 5;
    const int hk   = bh & 3;
    const int b    = bh >> 2;

    const int cnt = ((const int*)(ws + CNT_OFF))[b];
    const int nt  = (cnt + 63) >> 6;
    if (tile >= nt) return;

    const int tid = threadIdx.x;
    const int s4  = tid >> 4;              // 0..15
    const int d0  = (tid & 15) * 4;        // 0..60

    const int* cidx = (const int*)(ws + CIDX_OFF) + b * SK;
    bf16_t* Kt = (bf16_t*)(ws + KC_OFF + (size_t)bid * KTILE_BYTES);
    bf16_t* Vt = (bf16_t*)(ws + VC_OFF + (size_t)bid * KTILE_BYTES);

    f32x4 kk4[4], vv4[4];
    #pragma unroll
    for (int p = 0; p < 4; ++p) {
        const int crow = tile * NTILE + s4 * 4 + p;
        if (crow < cnt) {
            const int s = cidx[crow];
            const float* base = kv + (size_t)((b * SK + s) * 2) * (HKV * DD) + hk * DD + d0;
            kk4[p] = *(const f32x4*)base;
            vv4[p] = *(const f32x4*)(base + HKV * DD);
        } else {
            kk4[p] = (f32x4)(0.f);
            vv4[p] = (f32x4)(0.f);
        }
    }
    #pragma unroll
    for (int p = 0; p < 4; ++p) {
        bf16x4 kb;
        #pragma unroll
        for (int j = 0; j < 4; ++j) kb[j] = (bf16_t)kk4[p][j];
        *(bf16x4*)((char*)Kt + swzK(s4 * 4 + p, d0 * 2)) = kb;
    }
    #pragma unroll
    for (int j = 0; j < 4; ++j) {
        bf16x4 tv;
        #pragma unroll
        for (int p = 0; p < 4; ++p) tv[p] = (bf16_t)vv4[p][j];
        *(bf16x4*)((char*)Vt + swzK(d0 + j, s4 * 8)) = tv;   // V^T rows d
    }
}

// ---------------- main: 32x32 MFMA, in-register P, compacted KV --------------
__global__ __launch_bounds__(256, 2)
void fattn32c(const float* __restrict__ q, const char* __restrict__ ws,
              float* __restrict__ out)
{
    __shared__ __align__(16) bf16_t Ks[2][NTILE * 64];
    __shared__ __align__(16) bf16_t Vs[2][DD * 64];

    const int tid  = threadIdx.x;
    const int wid  = tid >> 6;
    const int lane = tid & 63;
    const int l31  = lane & 31;
    const int hf   = lane >> 5;
    const int ef   = lane & 7;

    // XCD-aware swizzle: 512 wgs, 8 XCDs, 64-wg chunks
    const int bid = (blockIdx.x & 7) * 64 + (blockIdx.x >> 3);
    const int qt  = bid & 15;
    const int bh  = bid >> 4;
    const int hq  = bh & 15;
    const int b   = bh >> 4;
    const int hk  = hq / GQ;

    const int cnt = ((const int*)(ws + CNT_OFF))[b];
    const int nt  = (cnt + 63) >> 6;

    const int qrow0 = qt * MTILE + wid * 32;
    const float SC = 0.18033688011112042f;   // 0.125 * log2(e)

    bf16x8 qf[4];
    {
        const float* qp = q + ((size_t)(b * SQ + qrow0 + l31) * NH + hq) * DD;
        #pragma unroll
        for (int kblk = 0; kblk < 4; ++kblk) {
            f32x4 v0 = *(const f32x4*)(qp + kblk * 16 + hf * 8);
            f32x4 v1 = *(const f32x4*)(qp + kblk * 16 + hf * 8 + 4);
            #pragma unroll
            for (int j = 0; j < 4; ++j) {
                qf[kblk][j]     = (bf16_t)(v0[j] * SC);
                qf[kblk][4 + j] = (bf16_t)(v1[j] * SC);
            }
        }
    }

    const char* kgb = ws + KC_OFF + (size_t)((b * HKV + hk) * MAXNT) * KTILE_BYTES;
    const char* vgb = ws + VC_OFF + (size_t)((b * HKV + hk) * MAXNT) * KTILE_BYTES;
    const float* padcb = (const float*)(ws + PADC_OFF) + b * SK;

    auto STAGE = [&](int t, int buf) {
        const char* ksrc = kgb + (size_t)t * KTILE_BYTES + wid * 2048 + lane * 16;
        const char* vsrc = vgb + (size_t)t * KTILE_BYTES + wid * 2048 + lane * 16;
        char* kdst = (char*)Ks[buf] + wid * 2048;
        char* vdst = (char*)Vs[buf] + wid * 2048;
        GLDS(ksrc, kdst);
        GLDS(ksrc + 1024, kdst + 1024);
        GLDS(vsrc, vdst);
        GLDS(vsrc + 1024, vdst + 1024);
    };

    STAGE(0, 0);

    int colX[4];
    #pragma unroll
    for (int kblk = 0; kblk < 4; ++kblk)
        colX[kblk] = (kblk * 32 + hf * 16) ^ (ef << 4);

    bf16x8 onesf;
    #pragma unroll
    for (int j = 0; j < 8; ++j) onesf[j] = (bf16_t)1.0f;

    f32x16 o0, o1, osum;
    #pragma unroll
    for (int i = 0; i < 16; ++i) { o0[i] = 0.f; o1[i] = 0.f; osum[i] = 0.f; }
    float m_run = 0.f;
    bool everR = false;

    for (int t = 0; t < nt; ++t) {
        const int cur = t & 1;
        if (t + 1 < nt) {
            STAGE(t + 1, cur ^ 1);
            asm volatile("s_waitcnt vmcnt(4)" ::: "memory");  // own tile-t loads done
        } else {
            asm volatile("s_waitcnt vmcnt(0)" ::: "memory");
        }
        __builtin_amdgcn_s_barrier();          // all waves' tile-t data landed
        __builtin_amdgcn_sched_barrier(0);

        // ---- init S accumulators (pad only on last tile)
        f32x16 s0, s1;
        if (t == nt - 1) {
            #pragma unroll
            for (int a = 0; a < 4; ++a) {
                f32x4 p0 = *(const f32x4*)(padcb + t * 64 + a * 8 + hf * 4);
                f32x4 p1 = *(const f32x4*)(padcb + t * 64 + 32 + a * 8 + hf * 4);
                if (everR) {
                    #pragma unroll
                    for (int c = 0; c < 4; ++c) { p0[c] -= m_run; p1[c] -= m_run; }
                }
                #pragma unroll
                for (int c = 0; c < 4; ++c) { s0[a * 4 + c] = p0[c]; s1[a * 4 + c] = p1[c]; }
            }
        } else {
            const float base = everR ? -m_run : 0.f;
            #pragma unroll
            for (int i = 0; i < 16; ++i) { s0[i] = base; s1[i] = base; }
        }

        // ---- QK^T (swapped): S^T[s][t] = K·Q^T
        __builtin_amdgcn_s_setprio(1);
        #pragma unroll
        for (int kblk = 0; kblk < 4; ++kblk) {
            bf16x8 kf0 = *(const bf16x8*)((char*)Ks[cur] + l31 * 128 + colX[kblk]);
            bf16x8 kf1 = *(const bf16x8*)((char*)Ks[cur] + 4096 + l31 * 128 + colX[kblk]);
            s0 = __builtin_amdgcn_mfma_f32_32x32x16_bf16(kf0, qf[kblk], s0, 0, 0, 0);
            s1 = __builtin_amdgcn_mfma_f32_32x32x16_bf16(kf1, qf[kblk], s1, 0, 0, 0);
        }
        __builtin_amdgcn_s_setprio(0);

        // ---- safety (defer-max): rescale only if scores leave [., 20]
        f32x16 mx;
        #pragma unroll
        for (int i = 0; i < 16; ++i) mx[i] = fmaxf(s0[i], s1[i]);
        #pragma unroll
        for (int off = 8; off > 0; off >>= 1) {
            #pragma unroll
            for (int i = 0; i < 8; ++i)
                if (i < off) mx[i] = fmaxf(mx[i], mx[i + off]);
        }
        const float rmax = mx[0];
        if (__any(rmax > 20.f)) {
            float rm2 = fmaxf(rmax, __shfl_xor(rmax, 32, 64));
            float delta = fmaxf(rm2, 0.f);
            #pragma unroll
            for (int i = 0; i < 16; ++i) { s0[i] -= delta; s1[i] -= delta; }
            float al = __builtin_amdgcn_exp2f(-delta);
            #pragma unroll
            for (int r = 0; r < 16; ++r) {
                const int t_r = (r & 3) + 8 * (r >> 2) + 4 * hf;
                float ar = __shfl(al, t_r + (lane & 32), 64);
                o0[r] *= ar; o1[r] *= ar; osum[r] *= ar;
            }
            m_run += delta;
            everR = true;
        }

        // ---- P = exp2(S)
        #pragma unroll
        for (int i = 0; i < 16; ++i) {
            s0[i] = __builtin_amdgcn_exp2f(s0[i]);
            s1[i] = __builtin_amdgcn_exp2f(s1[i]);
        }

        // ---- P -> A-frag in registers (cvt_pk + permlane32_swap)
        bf16x8 paw[4];
        #pragma unroll
        for (int ks2 = 0; ks2 < 4; ++ks2) {
            const int aX = (ks2 & 1) * 2;
            uint32_t X0, X1, Y0, Y1;
            #define CVTPK(dst, lo, hi) asm("v_cvt_pk_bf16_f32 %0, %1, %2" : "=v"(dst) : "v"(lo), "v"(hi))
            if (ks2 & 2) {
                CVTPK(X0, s1[4*aX + 0], s1[4*aX + 1]);
                CVTPK(X1, s1[4*aX + 2], s1[4*aX + 3]);
                CVTPK(Y0, s1[4*aX + 4], s1[4*aX + 5]);
                CVTPK(Y1, s1[4*aX + 6], s1[4*aX + 7]);
            } else {
                CVTPK(X0, s0[4*aX + 0], s0[4*aX + 1]);
                CVTPK(X1, s0[4*aX + 2], s0[4*aX + 3]);
                CVTPK(Y0, s0[4*aX + 4], s0[4*aX + 5]);
                CVTPK(Y1, s0[4*aX + 6], s0[4*aX + 7]);
            }
            #undef CVTPK
            asm("v_permlane32_swap_b32 %0, %1" : "+v"(X0), "+v"(Y0));
            asm("v_permlane32_swap_b32 %0, %1" : "+v"(X1), "+v"(Y1));
            union { u32x4 w; bf16x8 v; } u;
            u.w[0] = X0; u.w[1] = X1; u.w[2] = Y0; u.w[3] = Y1;
            paw[ks2] = u.v;
        }

        // ---- O += P V ; row sums via ones-MFMA
        __builtin_amdgcn_s_setprio(1);
        #pragma unroll
        for (int ks2 = 0; ks2 < 4; ++ks2) {
            bf16x8 vf0 = *(const bf16x8*)((char*)Vs[cur] + l31 * 128 + colX[ks2]);
            bf16x8 vf1 = *(const bf16x8*)((char*)Vs[cur] + 4096 + l31 * 128 + colX[ks2]);
            o0   = __builtin_amdgcn_mfma_f32_32x32x16_bf16(paw[ks2], vf0, o0, 0, 0, 0);
            o1   = __builtin_amdgcn_mfma_f32_32x32x16_bf16(paw[ks2], vf1, o1, 0, 0, 0);
            osum = __builtin_amdgcn_mfma_f32_32x32x16_bf16(paw[ks2], onesf, osum, 0, 0, 0);
        }
        __builtin_amdgcn_s_setprio(0);

        __builtin_amdgcn_sched_barrier(0);
        __builtin_amdgcn_s_barrier();          // all waves done reading buf[cur]
    }

    // ---- epilogue
    #pragma unroll
    for (int r = 0; r < 16; ++r) {
        const int t_r = (r & 3) + 8 * (r >> 2) + 4 * hf;
        const float sden = osum[r];
        const float linv = sden > 0.f ? 1.f / sden : 0.f;
        float* op = out + ((size_t)(b * SQ + qrow0 + t_r) * NH + hq) * DD + l31;
        op[0]  = o0[r] * linv;
        op[32] = o1[r] * linv;
    }
}

extern "C" void kernel_launch(void* const* d_in, const int* in_sizes, int n_in,
                              void* d_out, int out_size, void* d_ws, size_t ws_size,
                              hipStream_t stream) {
    const float* q    = (const float*)d_in[0];
    const float* kv   = (const float*)d_in[1];
    const int*   mask = (const int*)d_in[2];
    float* out = (float*)d_out;

    scan_kernel<<<BB, 256, 0, stream>>>(mask, (char*)d_ws);
    gather_kernel<<<BB * HKV * MAXNT, 256, 0, stream>>>(kv, (char*)d_ws);
    fattn32c<<<BB * NH * (SQ / MTILE), 256, 0, stream>>>(q, (const char*)d_ws, out);
}

// Round 6
// 42.022 us; speedup vs baseline: 4.1305x; 1.0377x over previous
//
#include <hip/hip_runtime.h>
#include <hip/hip_bf16.h>
#include <stdint.h>

typedef __bf16 bf16_t;
typedef bf16_t bf16x8 __attribute__((ext_vector_type(8)));
typedef bf16_t bf16x4 __attribute__((ext_vector_type(4)));
typedef float f32x4 __attribute__((ext_vector_type(4)));
typedef float f32x16 __attribute__((ext_vector_type(16)));
typedef uint32_t u32x4 __attribute__((ext_vector_type(4)));
typedef int   i32x4 __attribute__((ext_vector_type(4)));

#define BB 2
#define SQ 2048
#define SK 2048
#define NH 16
#define HKV 4
#define DD 64
#define GQ 4
#define MTILE 128           // q rows per block (32 per wave, 4 waves)
#define NTILE 64
#define MAXNT 32

#define KTILE_BYTES 8192
#define CNT_OFF   ((size_t)0)
#define CIDX_OFF  ((size_t)1024)
#define PADC_OFF  (CIDX_OFF + (size_t)BB * SK * 4)
#define KC_OFF    ((size_t)65536)
#define VC_OFF    (KC_OFF + (size_t)BB * HKV * MAXNT * KTILE_BYTES)

// 128B rows, XOR swizzle within row (16B granule)
__device__ __forceinline__ int swzK(int row, int colByte) {
    return row * 128 + (colByte ^ ((row & 7) << 4));
}

#define GLDS(g, l) __builtin_amdgcn_global_load_lds( \
    (const __attribute__((address_space(1))) void*)(g), \
    (__attribute__((address_space(3))) void*)(l), 16, 0, 0)

// ---------------- pass 1: per-b mask scan -> compacted index list ------------
__global__ __launch_bounds__(256)
void scan_kernel(const int* __restrict__ mask, char* __restrict__ ws)
{
    __shared__ int wtot[4];
    const int b    = blockIdx.x;
    const int tid  = threadIdx.x;
    const int lane = tid & 63;
    const int wid  = tid >> 6;

    int m[8], c = 0;
    {
        const int base = b * SK + tid * 8;
        i32x4 a0 = *(const i32x4*)&mask[base];
        i32x4 a1 = *(const i32x4*)&mask[base + 4];
        #pragma unroll
        for (int j = 0; j < 4; ++j) { m[j] = a0[j] ? 1 : 0; c += m[j]; }
        #pragma unroll
        for (int j = 0; j < 4; ++j) { m[4 + j] = a1[j] ? 1 : 0; c += m[4 + j]; }
    }
    int sc = c;
    #pragma unroll
    for (int off = 1; off < 64; off <<= 1) {
        int n = __shfl_up(sc, off, 64);
        if (lane >= off) sc += n;
    }
    if (lane == 63) wtot[wid] = sc;
    __syncthreads();
    int wbase = 0;
    #pragma unroll
    for (int w = 0; w < 4; ++w) if (w < wid) wbase += wtot[w];
    const int total = wtot[0] + wtot[1] + wtot[2] + wtot[3];

    int* cidx = (int*)(ws + CIDX_OFF) + b * SK;
    int pos = wbase + sc - c;
    #pragma unroll
    for (int j = 0; j < 8; ++j)
        if (m[j]) cidx[pos++] = tid * 8 + j;

    if (tid == 0) ((int*)(ws + CNT_OFF))[b] = total;

    float* padc = (float*)(ws + PADC_OFF) + b * SK;
    for (int i = tid; i < SK; i += 256)
        padc[i] = (i < total) ? 0.f : -30000.f;
}

// ---------------- pass 2: gather + f32->bf16 + transpose V + bake swizzle ----
__global__ __launch_bounds__(256)
void gather_kernel(const float* __restrict__ kv, char* __restrict__ ws)
{
    const int bid  = blockIdx.x;           // [b][hk][tile]
    const int tile = bid & 31;
    const int bh   = bid >> 5;
    const int hk   = bh & 3;
    const int b    = bh >> 2;

    const int cnt = ((const int*)(ws + CNT_OFF))[b];
    const int nt  = (cnt + 63) >> 6;
    if (tile >= nt) return;

    const int tid = threadIdx.x;
    const int s4  = tid >> 4;
    const int d0  = (tid & 15) * 4;

    const int* cidx = (const int*)(ws + CIDX_OFF) + b * SK;
    bf16_t* Kt = (bf16_t*)(ws + KC_OFF + (size_t)bid * KTILE_BYTES);
    bf16_t* Vt = (bf16_t*)(ws + VC_OFF + (size_t)bid * KTILE_BYTES);

    f32x4 kk4[4], vv4[4];
    #pragma unroll
    for (int p = 0; p < 4; ++p) {
        const int crow = tile * NTILE + s4 * 4 + p;
        if (crow < cnt) {
            const int s = cidx[crow];
            const float* base = kv + (size_t)((b * SK + s) * 2) * (HKV * DD) + hk * DD + d0;
            kk4[p] = *(const f32x4*)base;
            vv4[p] = *(const f32x4*)(base + HKV * DD);
        } else {
            kk4[p] = (f32x4)(0.f);
            vv4[p] = (f32x4)(0.f);
        }
    }
    #pragma unroll
    for (int p = 0; p < 4; ++p) {
        bf16x4 kb;
        #pragma unroll
        for (int j = 0; j < 4; ++j) kb[j] = (bf16_t)kk4[p][j];
        *(bf16x4*)((char*)Kt + swzK(s4 * 4 + p, d0 * 2)) = kb;
    }
    #pragma unroll
    for (int j = 0; j < 4; ++j) {
        bf16x4 tv;
        #pragma unroll
        for (int p = 0; p < 4; ++p) tv[p] = (bf16_t)vv4[p][j];
        *(bf16x4*)((char*)Vt + swzK(d0 + j, s4 * 8)) = tv;
    }
}

// ---------------- main: 2-tile pipelined, no-rescale softmax -----------------
__global__ __launch_bounds__(256, 2)
void fattn32p(const float* __restrict__ q, const char* __restrict__ ws,
              float* __restrict__ out)
{
    __shared__ __align__(16) bf16_t Ks[4][NTILE * 64];   // 32 KB
    __shared__ __align__(16) bf16_t Vs[4][DD * 64];      // 32 KB

    const int tid  = threadIdx.x;
    const int wid  = tid >> 6;
    const int lane = tid & 63;
    const int l31  = lane & 31;
    const int hf   = lane >> 5;
    const int ef   = lane & 7;

    // XCD-aware swizzle: 512 wgs, 8 XCDs, 64-wg chunks
    const int bid = (blockIdx.x & 7) * 64 + (blockIdx.x >> 3);
    const int qt  = bid & 15;
    const int bh  = bid >> 4;
    const int hq  = bh & 15;
    const int b   = bh >> 4;
    const int hk  = hq / GQ;

    const int cnt = ((const int*)(ws + CNT_OFF))[b];
    const int nt  = (cnt + 63) >> 6;

    const int qrow0 = qt * MTILE + wid * 32;
    const float SC = 0.18033688011112042f;   // 0.125 * log2(e)

    bf16x8 qf[4];
    {
        const float* qp = q + ((size_t)(b * SQ + qrow0 + l31) * NH + hq) * DD;
        #pragma unroll
        for (int kblk = 0; kblk < 4; ++kblk) {
            f32x4 v0 = *(const f32x4*)(qp + kblk * 16 + hf * 8);
            f32x4 v1 = *(const f32x4*)(qp + kblk * 16 + hf * 8 + 4);
            #pragma unroll
            for (int j = 0; j < 4; ++j) {
                qf[kblk][j]     = (bf16_t)(v0[j] * SC);
                qf[kblk][4 + j] = (bf16_t)(v1[j] * SC);
            }
        }
    }

    const char* kgb = ws + KC_OFF + (size_t)((b * HKV + hk) * MAXNT) * KTILE_BYTES;
    const char* vgb = ws + VC_OFF + (size_t)((b * HKV + hk) * MAXNT) * KTILE_BYTES;
    const float* padcb = (const float*)(ws + PADC_OFF) + b * SK;

    auto STAGE = [&](int t, int buf) {
        const char* ksrc = kgb + (size_t)t * KTILE_BYTES + wid * 2048 + lane * 16;
        const char* vsrc = vgb + (size_t)t * KTILE_BYTES + wid * 2048 + lane * 16;
        char* kdst = (char*)Ks[buf] + wid * 2048;
        char* vdst = (char*)Vs[buf] + wid * 2048;
        GLDS(ksrc, kdst);
        GLDS(ksrc + 1024, kdst + 1024);
        GLDS(vsrc, vdst);
        GLDS(vsrc + 1024, vdst + 1024);
    };

    int colX[4];
    #pragma unroll
    for (int kblk = 0; kblk < 4; ++kblk)
        colX[kblk] = (kblk * 32 + hf * 16) ^ (ef << 4);

    f32x16 o0, o1;
    #pragma unroll
    for (int i = 0; i < 16; ++i) { o0[i] = 0.f; o1[i] = 0.f; }
    float l_run = 0.f;    // in-lane partial denominator for col t = l31

    // ---- QK^T (swapped): S^T[s][t] = K·Q^T, pad pre-added via C-init
    auto QK = [&](int t, int buf, f32x16& s0, f32x16& s1) {
        if (t == nt - 1) {
            #pragma unroll
            for (int a = 0; a < 4; ++a) {
                f32x4 p0 = *(const f32x4*)(padcb + t * 64 + a * 8 + hf * 4);
                f32x4 p1 = *(const f32x4*)(padcb + t * 64 + 32 + a * 8 + hf * 4);
                #pragma unroll
                for (int c = 0; c < 4; ++c) { s0[a * 4 + c] = p0[c]; s1[a * 4 + c] = p1[c]; }
            }
        } else {
            #pragma unroll
            for (int i = 0; i < 16; ++i) { s0[i] = 0.f; s1[i] = 0.f; }
        }
        __builtin_amdgcn_s_setprio(1);
        #pragma unroll
        for (int kblk = 0; kblk < 4; ++kblk) {
            bf16x8 kf0 = *(const bf16x8*)((char*)Ks[buf] + l31 * 128 + colX[kblk]);
            bf16x8 kf1 = *(const bf16x8*)((char*)Ks[buf] + 4096 + l31 * 128 + colX[kblk]);
            s0 = __builtin_amdgcn_mfma_f32_32x32x16_bf16(kf0, qf[kblk], s0, 0, 0, 0);
            s1 = __builtin_amdgcn_mfma_f32_32x32x16_bf16(kf1, qf[kblk], s1, 0, 0, 0);
        }
        __builtin_amdgcn_s_setprio(0);
    };

    // ---- P = exp2(S); accumulate in-lane denom; pack A-frags in registers
    auto SM = [&](f32x16& s0, f32x16& s1, bf16x8* paw) {
        #pragma unroll
        for (int i = 0; i < 16; ++i) {
            s0[i] = __builtin_amdgcn_exp2f(s0[i]);
            s1[i] = __builtin_amdgcn_exp2f(s1[i]);
        }
        float t0 = 0.f, t1 = 0.f, t2 = 0.f, t3 = 0.f;
        #pragma unroll
        for (int i = 0; i < 4; ++i) {
            t0 += s0[i]      + s1[i];
            t1 += s0[4 + i]  + s1[4 + i];
            t2 += s0[8 + i]  + s1[8 + i];
            t3 += s0[12 + i] + s1[12 + i];
        }
        l_run += (t0 + t1) + (t2 + t3);

        #pragma unroll
        for (int ks2 = 0; ks2 < 4; ++ks2) {
            const int aX = (ks2 & 1) * 2;
            uint32_t X0, X1, Y0, Y1;
            #define CVTPK(dst, lo, hi) asm("v_cvt_pk_bf16_f32 %0, %1, %2" : "=v"(dst) : "v"(lo), "v"(hi))
            if (ks2 & 2) {
                CVTPK(X0, s1[4*aX + 0], s1[4*aX + 1]);
                CVTPK(X1, s1[4*aX + 2], s1[4*aX + 3]);
                CVTPK(Y0, s1[4*aX + 4], s1[4*aX + 5]);
                CVTPK(Y1, s1[4*aX + 6], s1[4*aX + 7]);
            } else {
                CVTPK(X0, s0[4*aX + 0], s0[4*aX + 1]);
                CVTPK(X1, s0[4*aX + 2], s0[4*aX + 3]);
                CVTPK(Y0, s0[4*aX + 4], s0[4*aX + 5]);
                CVTPK(Y1, s0[4*aX + 6], s0[4*aX + 7]);
            }
            #undef CVTPK
            asm("v_permlane32_swap_b32 %0, %1" : "+v"(X0), "+v"(Y0));
            asm("v_permlane32_swap_b32 %0, %1" : "+v"(X1), "+v"(Y1));
            union { u32x4 w; bf16x8 v; } u;
            u.w[0] = X0; u.w[1] = X1; u.w[2] = Y0; u.w[3] = Y1;
            paw[ks2] = u.v;
        }
    };

    auto PV = [&](int buf, const bf16x8* paw) {
        __builtin_amdgcn_s_setprio(1);
        #pragma unroll
        for (int ks2 = 0; ks2 < 4; ++ks2) {
            bf16x8 vf0 = *(const bf16x8*)((char*)Vs[buf] + l31 * 128 + colX[ks2]);
            bf16x8 vf1 = *(const bf16x8*)((char*)Vs[buf] + 4096 + l31 * 128 + colX[ks2]);
            o0 = __builtin_amdgcn_mfma_f32_32x32x16_bf16(paw[ks2], vf0, o0, 0, 0, 0);
            o1 = __builtin_amdgcn_mfma_f32_32x32x16_bf16(paw[ks2], vf1, o1, 0, 0, 0);
        }
        __builtin_amdgcn_s_setprio(0);
    };

    // ---- prologue staging
    STAGE(0, 0);
    if (1 < nt) STAGE(1, 1);

    int t = 0;
    for (; t + 1 < nt; t += 2) {
        const int n2 = (t + 2 < nt) ? 1 : 0;
        const int n3 = (t + 3 < nt) ? 1 : 0;
        if (n2) STAGE(t + 2, (t + 2) & 3);
        if (n3) STAGE(t + 3, (t + 3) & 3);
        if (n2 + n3 == 2)      asm volatile("s_waitcnt vmcnt(8)" ::: "memory");
        else if (n2 + n3 == 1) asm volatile("s_waitcnt vmcnt(4)" ::: "memory");
        else                   asm volatile("s_waitcnt vmcnt(0)" ::: "memory");
        __builtin_amdgcn_s_barrier();
        __builtin_amdgcn_sched_barrier(0);

        f32x16 sA0, sA1, sB0, sB1;
        bf16x8 pawA[4], pawB[4];
        QK(t,     t & 3,       sA0, sA1);
        QK(t + 1, (t + 1) & 3, sB0, sB1);
        SM(sA0, sA1, pawA);
        PV(t & 3, pawA);
        SM(sB0, sB1, pawB);
        PV((t + 1) & 3, pawB);

        __builtin_amdgcn_sched_barrier(0);
        __builtin_amdgcn_s_barrier();
    }
    if (t < nt) {   // odd-nt tail (tile already staged)
        asm volatile("s_waitcnt vmcnt(0)" ::: "memory");
        __builtin_amdgcn_s_barrier();
        __builtin_amdgcn_sched_barrier(0);
        f32x16 sA0, sA1;
        bf16x8 pawA[4];
        QK(t, t & 3, sA0, sA1);
        SM(sA0, sA1, pawA);
        PV(t & 3, pawA);
    }

    // ---- epilogue: combine halves of denom, normalize, store
    float lt = l_run + __shfl_xor(l_run, 32, 64);
    #pragma unroll
    for (int r = 0; r < 16; ++r) {
        const int t_r = (r & 3) + 8 * (r >> 2) + 4 * hf;
        const float den = __shfl(lt, t_r, 64);
        const float linv = den > 0.f ? 1.f / den : 0.f;
        float* op = out + ((size_t)(b * SQ + qrow0 + t_r) * NH + hq) * DD + l31;
        op[0]  = o0[r] * linv;
        op[32] = o1[r] * linv;
    }
}

extern "C" void kernel_launch(void* const* d_in, const int* in_sizes, int n_in,
                              void* d_out, int out_size, void* d_ws, size_t ws_size,
                              hipStream_t stream) {
    const float* q    = (const float*)d_in[0];
    const float* kv   = (const float*)d_in[1];
    const int*   mask = (const int*)d_in[2];
    float* out = (float*)d_out;

    scan_kernel<<<BB, 256, 0, stream>>>(mask, (char*)d_ws);
    gather_kernel<<<BB * HKV * MAXNT, 256, 0, stream>>>(kv, (char*)d_ws);
    fattn32p<<<BB * NH * (SQ / MTILE), 256, 0, stream>>>(q, (const char*)d_ws, out);
}